// Round 5
// baseline (121.046 us; speedup 1.0000x reference)
//
#include <hip/hip_runtime.h>
#include <cstdint>
#include <cmath>

// QuantumLatentLayer: out[b,q] = cos(a)*cos(theta_q) - sin(a)*(cos(phi_q)*sin(theta_q))
//                     a = sum_l latent[b,l]*W[q,l] + b_q
// M=32768, K=2048, N=24. HBM floor ~38 us @ 7 TB/s; VALU floor ~20.5 us.
//
// R2 lesson: per-lane W ds_reads dominate the DS pipe. R3 lesson: global_load_lds
// needs an explicit vmcnt wait before ds_read (no compiler-inserted wait without
// a barrier). R4 lesson: W-as-s_load batches (768 floats vs ~50 free SGPRs) =
// ~12 serial lgkm stalls/chunk, fatal at 2 waves/SIMD (VALUBusy 22%).
// v5: W in LDS read at WAVE-UNIFORM addresses (broadcast, no conflict, no
// scalar latency chains); lane = row for latent (2 ds_read_b128/chunk, source
// pre-swizzled for conflict-free reads); 8 waves/block x 6KB regions -> 48KB
// block, 2 blocks/CU = 4 waves/SIMD for latency hiding; per-wave private
// dbuf + vmcnt(0) drain at iteration top (R4-proven ordering).

#define NQ 24
#define LDIM 2048
#define BATCH 32768
#define KC 8              // k-chunk per buffer
#define TILE_ROWS 64      // rows per block == lanes
#define NWAVE 8           // waves per block = k-eighths
#define KSPAN (LDIM / NWAVE)    // 256
#define NCHUNK (KSPAN / KC)     // 32
#define REGF 1536         // floats per wave region (= 64*24 for reduction reuse)

typedef const __attribute__((address_space(1))) void* gas_t;
typedef __attribute__((address_space(3))) void* las_t;

__device__ __forceinline__ void gload_lds16(const float* g, float* l) {
    __builtin_amdgcn_global_load_lds((gas_t)g, (las_t)l, 16, 0, 0);
}
__device__ __forceinline__ void gload_lds4(const float* g, float* l) {
    __builtin_amdgcn_global_load_lds((gas_t)g, (las_t)l, 4, 0, 0);
}

// Latent tile [64 rows][8 floats] = 128 slots of 16B, 2 insts.
// Placement: (row l, half s) lives at phys slot p = (2l+s) ^ ((l>>2)&7).
// Bijective (verified by inverse below); read side: lane l's two b128s land
// 2 lanes/bank (free, m136). gload_lds writes slot sigma = 64*i + lane; source
// must supply the (row,half) that belongs there: q3=(sigma>>3)&7, t=sigma^q3,
// row=((sigma>>3)<<2)|((t>>1)&3), half=t&1.
__device__ __forceinline__ void stage_lat(const float* src, float* ldst, int lane) {
    #pragma unroll
    for (int i = 0; i < 2; i++) {
        const int sigma = 64 * i + lane;
        const int q3 = (sigma >> 3) & 7;
        const int t  = sigma ^ q3;
        const int rp = ((sigma >> 3) << 2) | ((t >> 1) & 3);
        const int s  = t & 1;
        gload_lds16(src + (size_t)rp * LDIM + 4 * s, ldst + i * 256);
    }
}

// W chunk [8 k][24 q] = 768 B contiguous, linear; 3 insts x 4B-width (256 B each).
__device__ __forceinline__ void stage_w(const float* wsrc, float* wdst, int lane) {
    #pragma unroll
    for (int i = 0; i < 3; i++)
        gload_lds4(wsrc + i * 64 + lane, wdst + i * 64);
}

// Lane owns row = lane, all 24 qubits. Per chunk: 2 own-row ds_read_b128
// (swizzle-corrected) + 48 wave-uniform W float4 reads (LDS broadcast) + 192 FMA.
__device__ __forceinline__ void compute_chunk(const float* __restrict__ lbuf,
                                              const float* __restrict__ wbuf,
                                              int lane, float (&acc)[NQ]) {
    const int q3 = (lane >> 2) & 7;
    const int p0 = (2 * lane) ^ q3;        // slot of (row=lane, half 0)
    float4 la = *(const float4*)(lbuf + 4 * p0);        // k-offsets 0..3
    float4 lb = *(const float4*)(lbuf + 4 * (p0 ^ 1));  // k-offsets 4..7
    #pragma unroll
    for (int j = 0; j < 8; j++) {
        const float a = (j < 4) ? ((const float*)&la)[j] : ((const float*)&lb)[j - 4];
        const float* wr = wbuf + j * NQ;   // wave-uniform
        #pragma unroll
        for (int m = 0; m < 6; m++) {
            float4 wv = *(const float4*)(wr + 4 * m);
            acc[4*m+0] = fmaf(a, wv.x, acc[4*m+0]);
            acc[4*m+1] = fmaf(a, wv.y, acc[4*m+1]);
            acc[4*m+2] = fmaf(a, wv.z, acc[4*m+2]);
            acc[4*m+3] = fmaf(a, wv.w, acc[4*m+3]);
        }
    }
}

__global__ __launch_bounds__(512, 4) void qll_main(
    const float* __restrict__ latent,
    const float* __restrict__ wt,    // [LDIM][NQ]
    const float* __restrict__ bvec,  // [NQ]
    const float* __restrict__ ctv,   // [NQ] cos(theta)
    const float* __restrict__ csv,   // [NQ] cos(phi)*sin(theta)
    float* __restrict__ out)
{
    // per-wave region: [0..511] lat dbuf, [1024? no:] layout below. 6 KB/wave,
    // 48 KB/block -> 2 blocks/CU (4 waves/SIMD).
    __shared__ __align__(16) float lds[NWAVE][REGF];

    const int tid  = threadIdx.x;
    const int wave = tid >> 6;
    const int lane = tid & 63;
    const int kq   = __builtin_amdgcn_readfirstlane(wave);  // k-eighth

    const int row0 = blockIdx.x * TILE_ROWS;
    const float* lsrc = latent + (size_t)row0 * LDIM + kq * KSPAN;
    const float* wsrc = wt + (size_t)kq * KSPAN * NQ;

    float* lat0 = &lds[wave][0];      // 512 floats
    float* lat1 = &lds[wave][512];    // 512 floats
    float* wb0  = &lds[wave][1024];   // 192 floats
    float* wb1  = &lds[wave][1216];   // 192 floats (1408..1535 pad)

    float acc[NQ];
    #pragma unroll
    for (int q = 0; q < NQ; q++) acc[q] = 0.0f;

    stage_lat(lsrc, lat0, lane);
    stage_w(wsrc, wb0, lane);

    #pragma unroll 1
    for (int c = 0; c < NCHUNK; c++) {
        // Drain ALL outstanding VMEM (buffer for chunk c guaranteed written).
        // What we drain was issued one full compute-phase ago; at 4 waves/SIMD
        // residual stall is covered by the other waves.
        asm volatile("s_waitcnt vmcnt(0)" ::: "memory");
        if (c + 1 < NCHUNK) {
            const int nb = (c & 1) ^ 1;   // next buffer
            stage_lat(lsrc + (c + 1) * KC, nb ? lat1 : lat0, lane);
            stage_w(wsrc + (size_t)(c + 1) * KC * NQ, nb ? wb1 : wb0, lane);
        }
        compute_chunk((c & 1) ? lat1 : lat0, (c & 1) ? wb1 : wb0, lane, acc);
    }

    // Wave's region is now dead -> reuse as red[64][24]; flat idx = row*24+q.
    {
        float* dst = &lds[wave][lane * NQ];   // 96 B stride, 16B-aligned
        #pragma unroll
        for (int v = 0; v < 6; v++)
            ((float4*)dst)[v] = make_float4(acc[4*v], acc[4*v+1], acc[4*v+2], acc[4*v+3]);
    }
    __syncthreads();

    // Epilogue: 1536 outputs/block; thread handles flat = tid + 512p (coalesced).
    #pragma unroll
    for (int p = 0; p < 3; p++) {
        const int flat = tid + 512 * p;
        const int r = flat / NQ;
        const int q = flat - NQ * r;
        float a = bvec[q];
        #pragma unroll
        for (int w = 0; w < NWAVE; w++) a += lds[w][flat];
        float s, co;
        __sincosf(a, &s, &co);
        out[(size_t)blockIdx.x * (TILE_ROWS * NQ) + flat] = co * ctv[q] - s * csv[q];
    }
}

// Prep: Wt[k][q] = W[q][k]; ctcs[0..23]=cos(theta), ctcs[24..47]=cos(phi)*sin(theta)
__global__ __launch_bounds__(256) void qll_prep(
    const float* __restrict__ W, const float* __restrict__ params,
    float* __restrict__ wt, float* __restrict__ ctcs)
{
    int idx = blockIdx.x * 256 + threadIdx.x;
    if (idx < LDIM * NQ) {
        int q = idx % NQ;
        int k = idx / NQ;
        wt[idx] = W[q * LDIM + k];
    }
    if (idx < NQ) {
        float phi = params[3 * idx + 0];
        float th  = params[3 * idx + 1];
        ctcs[idx]      = cosf(th);
        ctcs[NQ + idx] = cosf(phi) * sinf(th);
    }
}

extern "C" void kernel_launch(void* const* d_in, const int* in_sizes, int n_in,
                              void* d_out, int out_size, void* d_ws, size_t ws_size,
                              hipStream_t stream) {
    (void)in_sizes; (void)n_in; (void)out_size; (void)ws_size;
    const float* latent = (const float*)d_in[0];
    const float* W      = (const float*)d_in[1];
    const float* bvec   = (const float*)d_in[2];
    const float* params = (const float*)d_in[3];
    float* out  = (float*)d_out;
    float* wt   = (float*)d_ws;              // LDIM*NQ floats
    float* ctcs = wt + LDIM * NQ;            // 2*NQ floats

    hipLaunchKernelGGL(qll_prep, dim3((LDIM * NQ + 255) / 256), dim3(256), 0, stream,
                       W, params, wt, ctcs);
    hipLaunchKernelGGL(qll_main, dim3(BATCH / TILE_ROWS), dim3(512), 0, stream,
                       latent, wt, bvec, ctcs, ctcs + NQ, out);
}